// Round 5
// baseline (234.012 us; speedup 1.0000x reference)
//
#include <hip/hip_runtime.h>
#include <math.h>

#define NH     12
#define BB     2
#define SEQ    2048
#define DMODEL 768
#define DK     64

typedef __attribute__((ext_vector_type(8))) short short8;   // 8 bf16 = 4 VGPRs
typedef __attribute__((ext_vector_type(4))) short short4v;  // 4 bf16 = 8 B
typedef __attribute__((ext_vector_type(4))) float floatx4;  // MFMA acc

__device__ __forceinline__ unsigned short f2bf(float x) {
    unsigned u = __builtin_bit_cast(unsigned, x);
    u = (u + 0x7fffu + ((u >> 16) & 1u)) >> 16;   // round-to-nearest-even
    return (unsigned short)u;
}
__device__ __forceinline__ unsigned short f2bf_fast(float x) {
    unsigned u = __builtin_bit_cast(unsigned, x);
    return (unsigned short)((u + 0x8000u) >> 16);
}

// async global -> LDS, 16 B per lane. Dest is wave-uniform base + lane*16.
__device__ __forceinline__ void gld_lds16(const ushort* gptr, ushort* lptr) {
    __builtin_amdgcn_global_load_lds(
        (const __attribute__((address_space(1))) unsigned int*)(const void*)gptr,
        (__attribute__((address_space(3))) unsigned int*)(void*)lptr,
        16, 0, 0);
}

#define SI (BB * SEQ * DMODEL)     // 3,145,728
#define SW (DMODEL * DMODEL)       //   589,824

// ---------------------------------------------------------------------------
// cast weights fp32 -> bf16 (9.4 MB total). Also zeroes the steal counter.
// ---------------------------------------------------------------------------
__global__ __launch_bounds__(256) void cast_w(
    const float* __restrict__ Wq, const float* __restrict__ Wk,
    const float* __restrict__ Wv, const float* __restrict__ Wo,
    ushort* oWq, ushort* oWk, ushort* oWv, ushort* oWo, int* counter) {
    if (blockIdx.x == 0 && threadIdx.x == 0) *counter = 0;
    long i = (long)(blockIdx.x * 256 + threadIdx.x) * 4;
    const float* src; ushort* dst; long off;
    if      (i < 1L * SW) { src = Wq; dst = oWq; off = i; }
    else if (i < 2L * SW) { src = Wk; dst = oWk; off = i - 1L * SW; }
    else if (i < 3L * SW) { src = Wv; dst = oWv; off = i - 2L * SW; }
    else                  { src = Wo; dst = oWo; off = i - 3L * SW; }
    float4 v = *(const float4*)(src + off);
    ushort4 o;
    o.x = f2bf(v.x); o.y = f2bf(v.y); o.z = f2bf(v.z); o.w = f2bf(v.w);
    *(ushort4*)(dst + off) = o;
}

// ---------------------------------------------------------------------------
// bf16 MFMA GEMM: C = A[M,768] @ W[768,768]^T.  128x128 tile, BK=32 double-
// buffered, XOR-swizzled LDS, 1 barrier/step. W staged via global_load_lds.
// AF32: A is fp32 in global; converted to bf16 during register-staged LDS write.
// MODE 0: fp32 out row-major.  MODE 1: bf16 out split-head (b,h,s,dk) * scale.
// MODE 2: bf16 out TRANSPOSED split-head (b,h,dk,s) via MFMA operand swap.
// ---------------------------------------------------------------------------
template<int MODE, bool AF32>
__device__ __forceinline__ void gemm_body(const void* __restrict__ Av,
                                          const ushort* __restrict__ W,
                                          float* __restrict__ outF,
                                          ushort* __restrict__ outH,
                                          float scale) {
    const int n0 = blockIdx.x * 128;
    const int m0 = blockIdx.y * 128;
    const int tid  = threadIdx.x;
    const int lane = tid & 63;
    const int wv   = tid >> 6;
    const int l15  = lane & 15;
    const int quad = lane >> 4;
    const int wm = (wv >> 1) * 64;
    const int wn = (wv & 1) * 64;

    __shared__ __align__(16) ushort S[2][2][128 * 32];   // [buf][A/W] = 32 KB

    const int srow = tid >> 2;                   // 0..63
    const int sch  = tid & 3;                    // dest chunk (8 shorts)
    const int schx = sch ^ ((srow >> 1) & 3);    // swizzled source chunk
    const int sw2  = (l15 >> 1) & 3;             // read-side swizzle term

    const ushort* Ab = (const ushort*)Av;        // bf16 path
    const float*  Af = (const float*)Av;         // fp32 path

    floatx4 acc[4][4];
    #pragma unroll
    for (int i = 0; i < 4; ++i)
        #pragma unroll
        for (int j = 0; j < 4; ++j) acc[i][j] = (floatx4)0.f;

    float4 ar0[2], ar1[2];
    // prologue: step 0 -> buf 0
    #pragma unroll
    for (int it = 0; it < 2; ++it) {
        const int r = srow + it * 64;
        if (AF32) {
            const float* p = Af + (size_t)(m0 + r) * DMODEL + schx * 8;
            ar0[it] = *(const float4*)p;
            ar1[it] = *(const float4*)(p + 4);
        } else {
            gld_lds16(Ab + (size_t)(m0 + r) * DMODEL + schx * 8, &S[0][0][r * 32 + sch * 8]);
        }
        gld_lds16(W + (size_t)(n0 + r) * DMODEL + schx * 8, &S[0][1][r * 32 + sch * 8]);
    }
    if (AF32) {
        #pragma unroll
        for (int it = 0; it < 2; ++it) {
            const int r = srow + it * 64;
            short8 s8;
            s8[0] = (short)f2bf(ar0[it].x); s8[1] = (short)f2bf(ar0[it].y);
            s8[2] = (short)f2bf(ar0[it].z); s8[3] = (short)f2bf(ar0[it].w);
            s8[4] = (short)f2bf(ar1[it].x); s8[5] = (short)f2bf(ar1[it].y);
            s8[6] = (short)f2bf(ar1[it].z); s8[7] = (short)f2bf(ar1[it].w);
            *(short8*)&S[0][0][r * 32 + sch * 8] = s8;
        }
    }

    const int NS = DMODEL / 32;
    for (int t = 0; t < NS; ++t) {
        __syncthreads();
        const int bi = (t + 1) & 1;
        if (t + 1 < NS) {
            const int k0 = (t + 1) * 32;
            #pragma unroll
            for (int it = 0; it < 2; ++it) {
                const int r = srow + it * 64;
                if (AF32) {
                    const float* p = Af + (size_t)(m0 + r) * DMODEL + k0 + schx * 8;
                    ar0[it] = *(const float4*)p;
                    ar1[it] = *(const float4*)(p + 4);
                } else {
                    gld_lds16(Ab + (size_t)(m0 + r) * DMODEL + k0 + schx * 8, &S[bi][0][r * 32 + sch * 8]);
                }
                gld_lds16(W + (size_t)(n0 + r) * DMODEL + k0 + schx * 8, &S[bi][1][r * 32 + sch * 8]);
            }
        }
        const ushort* As  = S[t & 1][0];
        const ushort* Ws2 = S[t & 1][1];
        short8 af[4], bf[4];
        #pragma unroll
        for (int mi = 0; mi < 4; ++mi)
            af[mi] = *(const short8*)&As[(wm + mi * 16 + l15) * 32 + ((quad ^ sw2) * 8)];
        #pragma unroll
        for (int ni = 0; ni < 4; ++ni)
            bf[ni] = *(const short8*)&Ws2[(wn + ni * 16 + l15) * 32 + ((quad ^ sw2) * 8)];
        #pragma unroll
        for (int mi = 0; mi < 4; ++mi)
            #pragma unroll
            for (int ni = 0; ni < 4; ++ni) {
                if (MODE == 2)
                    acc[mi][ni] = __builtin_amdgcn_mfma_f32_16x16x32_bf16(bf[ni], af[mi], acc[mi][ni], 0, 0, 0);
                else
                    acc[mi][ni] = __builtin_amdgcn_mfma_f32_16x16x32_bf16(af[mi], bf[ni], acc[mi][ni], 0, 0, 0);
            }
        if (AF32 && t + 1 < NS) {
            #pragma unroll
            for (int it = 0; it < 2; ++it) {
                const int r = srow + it * 64;
                short8 s8;
                s8[0] = (short)f2bf(ar0[it].x); s8[1] = (short)f2bf(ar0[it].y);
                s8[2] = (short)f2bf(ar0[it].z); s8[3] = (short)f2bf(ar0[it].w);
                s8[4] = (short)f2bf(ar1[it].x); s8[5] = (short)f2bf(ar1[it].y);
                s8[6] = (short)f2bf(ar1[it].z); s8[7] = (short)f2bf(ar1[it].w);
                *(short8*)&S[bi][0][r * 32 + sch * 8] = s8;
            }
        }
    }

    #pragma unroll
    for (int mi = 0; mi < 4; ++mi)
        #pragma unroll
        for (int ni = 0; ni < 4; ++ni)
            #pragma unroll
            for (int r = 0; r < 4; ++r) {
                const float v = acc[mi][ni][r] * scale;
                if (MODE == 2) {
                    const int m = m0 + wm + mi * 16 + l15;          // seq dim
                    const int n = n0 + wn + ni * 16 + quad * 4 + r; // feature dim
                    const int b = m >> 11, s = m & (SEQ - 1);
                    const int h = n >> 6,  dk = n & 63;
                    outH[(((size_t)b * NH + h) * DK + dk) * SEQ + s] = f2bf(v);
                } else {
                    const int m = m0 + wm + mi * 16 + quad * 4 + r;
                    const int n = n0 + wn + ni * 16 + l15;
                    if (MODE == 0) {
                        outF[(size_t)m * DMODEL + n] = v;
                    } else {
                        const int b = m >> 11, s = m & (SEQ - 1);
                        const int h = n >> 6,  dk = n & 63;
                        outH[(((size_t)b * NH + h) * SEQ + s) * DK + dk] = f2bf(v);
                    }
                }
            }
}

// scale for Q: 1/sqrt(64) * log2(e) -> softmax uses exp2 directly
#define QSCALE (0.125f * 1.44269504088896f)

__global__ __launch_bounds__(256) void gemm_qkv(
    const float* Q, const float* K, const float* V,
    const ushort* Wqb, const ushort* Wkb, const ushort* Wvb,
    ushort* qh, ushort* kh, ushort* vhT) {
    const int z = blockIdx.z;
    if (z == 0)      gemm_body<1, true>(Q, Wqb, nullptr, qh,  QSCALE);
    else if (z == 1) gemm_body<1, true>(K, Wkb, nullptr, kh,  1.0f);
    else             gemm_body<2, true>(V, Wvb, nullptr, vhT, 1.0f);
}

__global__ __launch_bounds__(256) void gemm_out(const ushort* A, const ushort* W, float* out) {
    gemm_body<0, false>(A, W, out, nullptr, 1.0f);
}

// ---------------------------------------------------------------------------
// MFMA flash attention (causal), 8 waves / 512 threads per block.
// Wave group g = wv>>2 handles q-tile 2*qp+g; both groups share one K/V^T
// double-buffer. Work-stealing over 384 (bh, q-pair) items, heavy first.
// QK^T computed transposed (C[key][query]) -> key-reduce is in-lane + 2 shuffles.
// log2e/sqrt(dk) pre-folded into q. Writes ctx bf16 (B,S,D).
// ---------------------------------------------------------------------------
#define NITEMS (24 * 16)

__global__ __launch_bounds__(512) void flash_mfma(const ushort* __restrict__ qh,
                                                  const ushort* __restrict__ kh,
                                                  const ushort* __restrict__ vhT,
                                                  ushort* __restrict__ ctx,
                                                  int* __restrict__ counter) {
    const int tid  = threadIdx.x;
    const int lane = tid & 63;
    const int wv   = tid >> 6;            // 0..7
    const int grp  = wv >> 2;             // q-tile group 0/1
    const int l15  = lane & 15;
    const int quad = lane >> 4;

    __shared__ __align__(16) ushort KV[2][2][64 * 64];   // [buf][K / V^T] = 32 KB
    __shared__ __align__(16) ushort Ps[8][16 * 72];      // per-wave P tile = 18 KB
    __shared__ int wshare;

    const int srow = tid >> 3;            // 0..63 (512 threads cover a whole tile)
    const int sch  = tid & 7;             // dest chunk (8 shorts)
    const int schx = sch ^ (srow & 7);    // swizzled source chunk
    const int swq  = l15 & 7;             // read-side swizzle term

    for (;;) {
        if (tid == 0) wshare = atomicAdd(counter, 1);
        __syncthreads();                   // publishes wshare; ends prev item's LDS use
        const int w = wshare;
        if (w >= NITEMS) break;
        const int qp = 15 - (w / 24);      // heavy pairs first
        const int bh = w - (w / 24) * 24;
        const int b  = bh / NH, h = bh % NH;
        const int qt = 2 * qp + grp;       // this group's q-tile
        const int q0 = qt * 64;
        const int ktmax = 2 * qp + 1;      // k-tiles 0..ktmax staged (group 1's range)

        const ushort* kbase = kh  + (size_t)bh * SEQ * DK;
        const ushort* vbase = vhT + (size_t)bh * DK * SEQ;

        // Q fragment (B-operand layout): query = (wv&3)*16 + l15
        short8 q_frag[2];
        {
            const ushort* qp_ = qh + ((size_t)bh * SEQ + q0 + (wv & 3) * 16 + l15) * DK;
            q_frag[0] = *(const short8*)(qp_ + quad * 8);
            q_frag[1] = *(const short8*)(qp_ + 32 + quad * 8);
        }

        // prologue: tile 0 -> buf 0 (one instruction each for K and V^T)
        gld_lds16(kbase + (size_t)srow * DK + schx * 8,  &KV[0][0][srow * 64 + sch * 8]);
        gld_lds16(vbase + (size_t)srow * SEQ + schx * 8, &KV[0][1][srow * 64 + sch * 8]);

        float m_s = -3.0e38f, l_s = 0.f;   // per-lane: query = (wv&3)*16 + l15
        floatx4 o_acc[4];
        #pragma unroll
        for (int d = 0; d < 4; ++d) o_acc[d] = (floatx4)0.f;

        for (int kt = 0; kt <= ktmax; ++kt) {
            __syncthreads();               // drains tile-kt loads
            if (kt < ktmax) {
                const int k0 = (kt + 1) * 64;
                const int bi = (kt + 1) & 1;
                gld_lds16(kbase + (size_t)(k0 + srow) * DK + schx * 8, &KV[bi][0][srow * 64 + sch * 8]);
                gld_lds16(vbase + (size_t)srow * SEQ + k0 + schx * 8,  &KV[bi][1][srow * 64 + sch * 8]);
            }
            if (kt > qt) continue;         // group 0 idles on group 1's last tile
            const ushort* Ks  = KV[kt & 1][0];
            const ushort* Vts = KV[kt & 1][1];

            // S^T = K . q^T : C[key = nt*16 + quad*4 + r][query = l15]
            floatx4 s_acc[4];
            #pragma unroll
            for (int nt = 0; nt < 4; ++nt) s_acc[nt] = (floatx4)0.f;
            #pragma unroll
            for (int kc = 0; kc < 2; ++kc)
                #pragma unroll
                for (int nt = 0; nt < 4; ++nt) {
                    short8 kf = *(const short8*)&Ks[(nt * 16 + l15) * 64 + (((kc * 4 + quad) ^ swq) * 8)];
                    s_acc[nt] = __builtin_amdgcn_mfma_f32_16x16x32_bf16(kf, q_frag[kc], s_acc[nt], 0, 0, 0);
                }

            // causal mask (diagonal tile): key_local > query_local
            if (kt == qt) {
                const int ql = (wv & 3) * 16 + l15;
                #pragma unroll
                for (int nt = 0; nt < 4; ++nt)
                    #pragma unroll
                    for (int r = 0; r < 4; ++r)
                        if (nt * 16 + quad * 4 + r > ql) s_acc[nt][r] = -1.0e30f;
            }

            // online softmax: in-lane reduce (16 vals) + 2 cross-quad shuffles
            float mx = s_acc[0][0];
            #pragma unroll
            for (int nt = 0; nt < 4; ++nt)
                #pragma unroll
                for (int r = 0; r < 4; ++r) mx = fmaxf(mx, s_acc[nt][r]);
            mx = fmaxf(mx, __shfl_xor(mx, 16));
            mx = fmaxf(mx, __shfl_xor(mx, 32));
            const float mnew = fmaxf(m_s, mx);
            const float al = exp2f(m_s - mnew);
            m_s = mnew;
            float rs = 0.f;
            #pragma unroll
            for (int nt = 0; nt < 4; ++nt) {
                short4v pk;
                #pragma unroll
                for (int r = 0; r < 4; ++r) {
                    const float p = exp2f(s_acc[nt][r] - mnew);
                    rs += p;
                    pk[r] = (short)f2bf_fast(p);
                }
                *(short4v*)&Ps[wv][l15 * 72 + nt * 16 + quad * 4] = pk;
            }
            rs += __shfl_xor(rs, 16);
            rs += __shfl_xor(rs, 32);
            l_s = l_s * al + rs;

            // alpha for O rows (query = (wv&3)*16 + quad*4 + r)
            #pragma unroll
            for (int r = 0; r < 4; ++r) {
                const float ar = __shfl(al, quad * 20 + r);
                #pragma unroll
                for (int d = 0; d < 4; ++d) o_acc[d][r] *= ar;
            }

            // O += P @ V
            #pragma unroll
            for (int kc = 0; kc < 2; ++kc) {
                short8 pf = *(const short8*)&Ps[wv][l15 * 72 + kc * 32 + quad * 8];
                #pragma unroll
                for (int dkt = 0; dkt < 4; ++dkt) {
                    short8 vf = *(const short8*)&Vts[(dkt * 16 + l15) * 64 + (((kc * 4 + quad) ^ swq) * 8)];
                    o_acc[dkt] = __builtin_amdgcn_mfma_f32_16x16x32_bf16(pf, vf, o_acc[dkt], 0, 0, 0);
                }
            }
        }

        // finalize: O rows = q0 + (wv&3)*16 + quad*4 + r, cols dk = dkt*16 + l15
        #pragma unroll
        for (int r = 0; r < 4; ++r) {
            const float lr = __shfl(l_s, quad * 20 + r);
            const float inv = 1.f / lr;
            const int s = q0 + (wv & 3) * 16 + quad * 4 + r;
            #pragma unroll
            for (int dkt = 0; dkt < 4; ++dkt) {
                const int d = h * DK + dkt * 16 + l15;
                ctx[((size_t)b * SEQ + s) * DMODEL + d] = f2bf(o_acc[dkt][r] * inv);
            }
        }
    }
}

// ---------------------------------------------------------------------------
extern "C" void kernel_launch(void* const* d_in, const int* in_sizes, int n_in,
                              void* d_out, int out_size, void* d_ws, size_t ws_size,
                              hipStream_t stream) {
    const float* Q  = (const float*)d_in[0];
    const float* K  = (const float*)d_in[1];
    const float* V  = (const float*)d_in[2];
    const float* Wq = (const float*)d_in[4];
    const float* Wk = (const float*)d_in[5];
    const float* Wv = (const float*)d_in[6];
    const float* Wo = (const float*)d_in[7];

    char* ws = (char*)d_ws;
    const size_t SZ_IN = (size_t)SI * 2;
    const size_t SZ_W  = (size_t)SW * 2;
    ushort* Wqb = (ushort*)(ws);
    ushort* Wkb = (ushort*)(ws + SZ_W);
    ushort* Wvb = (ushort*)(ws + 2 * SZ_W);
    ushort* Wob = (ushort*)(ws + 3 * SZ_W);
    ushort* qh  = (ushort*)(ws + 4 * SZ_W);
    ushort* kh  = (ushort*)(ws + 4 * SZ_W + SZ_IN);
    ushort* vhT = (ushort*)(ws + 4 * SZ_W + 2 * SZ_IN);
    ushort* ctx = (ushort*)(ws + 4 * SZ_W + 3 * SZ_IN);
    int*    ctr = (int*)   (ws + 4 * SZ_W + 4 * SZ_IN);

    dim3 blk(256);
    cast_w<<<dim3(4 * SW / 1024), blk, 0, stream>>>(Wq, Wk, Wv, Wo,
                                                    Wqb, Wkb, Wvb, Wob, ctr);
    gemm_qkv<<<dim3(6, 32, 3), blk, 0, stream>>>(Q, K, V, Wqb, Wkb, Wvb, qh, kh, vhT);
    flash_mfma<<<dim3(768), dim3(512), 0, stream>>>(qh, kh, vhT, ctx, ctr);
    gemm_out<<<dim3(6, 32), blk, 0, stream>>>(ctx, Wob, (float*)d_out);
}